// Round 5
// baseline (700.036 us; speedup 1.0000x reference)
//
#include <hip/hip_runtime.h>
#include <hip/hip_bf16.h>
#include <math.h>
#include <stdint.h>

// Problem constants
#define BB   256
#define NN   180
#define CC   768
#define RR   192
#define MROWS (BB*NN)      // 46080 flat rows
#define KPAD 192           // node-dim padded to 192 for GEMM3 K

typedef __attribute__((ext_vector_type(8))) __bf16 bf16x8;
typedef __attribute__((ext_vector_type(4))) __bf16 bf16x4;
typedef __attribute__((ext_vector_type(4))) float  floatx4;

// async global->LDS, 16 B per lane. LDS dest is wave-uniform base + lane*16.
__device__ __forceinline__ void gload_lds16(const __bf16* g, __bf16* lds)
{
    __builtin_amdgcn_global_load_lds(
        (const __attribute__((address_space(1))) void*)(uintptr_t)(const void*)g,
        (__attribute__((address_space(3))) void*)(uintptr_t)(void*)lds,
        16, 0, 0);
}

// ---------------------------------------------------------------------------
// gemm256m: 256(M)x128(N) tile, 4 waves (2x2), each wave owns a 128x64 patch
// (8x4 grid of 16x16x32 MFMA -> 32 MFMA + 12 ds_read_b128 per epoch, i.e.
// 2x FLOP per epoch vs the 64x64 patch: halves per-epoch fixed cost and
// LDS-read bytes per FLOP). Requires M%256==0, N%128==0, K%32==0 (exact).
// 3-slot LDS ring + counted vmcnt(6): slot c+2 issued at top of epoch c,
// end-of-epoch wait leaves the newest 6 loads in flight (T4). T2 source-
// preswizzle (bank conflicts measured 0), T1 bijective XCD chunking.
// LDS = 3 x (16KB A + 8KB B) = 72 KB dynamic -> 2 blocks/CU, 2 waves/SIMD.
// MODE 0: out bf16, val=(acc+bias[n])*scale[n]            (Q/K projection)
// MODE 3: out f32,  val=relu(acc+bias[n]) + addx[m*ldc+n]  (z@Wg + residual)
// ---------------------------------------------------------------------------
template<int MODE>
__global__ __launch_bounds__(256, 2) void gemm256m(
    const __bf16* __restrict__ A,  int lda,
    const __bf16* __restrict__ Bt, int ldb,
    void* __restrict__ Cout, int ldc,
    int M, int N, int K,
    const float* __restrict__ bias,
    const float* __restrict__ scale,
    const float* __restrict__ addx)
{
    extern __shared__ __align__(16) __bf16 smem[];
    __bf16 (*sa)[256 * 32] = (__bf16 (*)[256 * 32])(smem);            // 3 x 16 KB
    __bf16 (*sb)[128 * 32] = (__bf16 (*)[128 * 32])(smem + 3 * 8192); // 3 x 8 KB

    // T1: bijective XCD chunking over the xy grid
    const int nwg = gridDim.x * gridDim.y;
    const int lin = blockIdx.y * gridDim.x + blockIdx.x;
    const int qd = nwg >> 3, rr = nwg & 7, xc = lin & 7, oo = lin >> 3;
    const int wg = (xc < rr ? xc * (qd + 1) : rr * (qd + 1) + (xc - rr) * qd) + oo;
    const int m0 = (wg / gridDim.x) * 256;
    const int n0 = (wg % gridDim.x) * 128;

    const int t  = threadIdx.x;
    const int w  = t >> 6;
    const int l  = t & 63;
    const int lr = l & 15;
    const int q  = l >> 4;
    const int xr = (lr >> 1) & 3;          // read-side swizzle factor

    floatx4 acc[8][4] = {};

    const int wm = (w >> 1) * 128;   // wave's m-offset within tile (0/128)
    const int wn = (w & 1) * 64;     // wave's n-offset within tile (0/64)

    // staging lane map: chunk = 16 rows x 32 k (1024 B); lane l -> row l>>2,
    // phys slot l&3 holds logical slot (l&3)^((l>>3)&3)  (source pre-swizzle)
    const int srow = l >> 2;
    const int skc  = ((l & 3) ^ ((l >> 3) & 3)) * 8;

    // A: 16 chunks of 16 rows; wave w stages chunks {w, w+4, w+8, w+12}
    // B:  8 chunks;            wave w stages chunks {w, w+4}
    const __bf16* agp[4];
#pragma unroll
    for (int c = 0; c < 4; ++c)
        agp[c] = A + (long)(m0 + c * 64 + w * 16 + srow) * lda + skc;
    const __bf16* bgp[2];
#pragma unroll
    for (int c = 0; c < 2; ++c)
        bgp[c] = Bt + (long)(n0 + c * 64 + w * 16 + srow) * ldb + skc;

    // issue chunk cc (32 k-elems) into ring slot: 6 gload_lds per wave
    auto issue = [&](int slot, int cc) {
        const int k0 = cc * 32;
#pragma unroll
        for (int c = 0; c < 4; ++c)
            gload_lds16(agp[c] + k0, &sa[slot][(size_t)(c * 4 + w) * 512]);
#pragma unroll
        for (int c = 0; c < 2; ++c)
            gload_lds16(bgp[c] + k0, &sb[slot][(size_t)(c * 4 + w) * 512]);
    };

    auto compute = [&](int slot) {
        bf16x8 af[8], bfv[4];
#pragma unroll
        for (int i = 0; i < 8; ++i)
            af[i] = *reinterpret_cast<const bf16x8*>(
                &sa[slot][(wm + i * 16 + lr) * 32 + ((q ^ xr) * 8)]);
#pragma unroll
        for (int j = 0; j < 4; ++j)
            bfv[j] = *reinterpret_cast<const bf16x8*>(
                &sb[slot][(wn + j * 16 + lr) * 32 + ((q ^ xr) * 8)]);
#pragma unroll
        for (int i = 0; i < 8; ++i)
#pragma unroll
            for (int j = 0; j < 4; ++j)
                acc[i][j] = __builtin_amdgcn_mfma_f32_16x16x32_bf16(af[i], bfv[j], acc[i][j], 0, 0, 0);
    };

    const int NC = K >> 5;   // 32-k chunks (24 for K=768)

    // prologue: slots 0,1 in flight (12 loads); wait for slot 0 only
    issue(0, 0);
    issue(1, 1);
    asm volatile("s_waitcnt vmcnt(6)" ::: "memory");
    __builtin_amdgcn_sched_barrier(0);
    __builtin_amdgcn_s_barrier();
    __builtin_amdgcn_sched_barrier(0);

#pragma unroll 3
    for (int c = 0; c < NC; ++c) {
        const int cs = c % 3;            // compute slot
        if (c + 2 < NC) issue((c + 2) % 3, c + 2);
        compute(cs);
        if (c + 1 < NC) {
            if (c + 2 < NC) asm volatile("s_waitcnt vmcnt(6)" ::: "memory");
            else            asm volatile("s_waitcnt vmcnt(0)" ::: "memory");
            __builtin_amdgcn_sched_barrier(0);
            __builtin_amdgcn_s_barrier();
            __builtin_amdgcn_sched_barrier(0);
        }
    }

    // epilogue: D subtile (i,j): row = q*4+r, col = lr. Grid divides exactly.
#pragma unroll
    for (int j = 0; j < 4; ++j) {
        const int n = n0 + wn + j * 16 + lr;
        const float bi = bias[n];
        const float sc = (MODE == 0) ? scale[n] : 1.0f;
#pragma unroll
        for (int i = 0; i < 8; ++i) {
            const int mbase = m0 + wm + i * 16 + q * 4;
#pragma unroll
            for (int r = 0; r < 4; ++r) {
                const int m = mbase + r;
                float v = acc[i][j][r];
                if (MODE == 0) {
                    v = (v + bi) * sc;
                    ((__bf16*)Cout)[(long)m * ldc + n] = (__bf16)v;
                } else { // MODE 3
                    v = v + bi;
                    v = v > 0.f ? v : 0.f;
                    v += addx[(long)m * ldc + n];
                    ((float*)Cout)[(long)m * ldc + n] = v;
                }
            }
        }
    }
}

// ---------------------------------------------------------------------------
// 128x128-tile bf16 MFMA GEMM (kept for batched small-M GEMMs 2 and 3).
// 3-slot counted-vmcnt ring; T2 swizzle; T1 XCD chunking.
// MODE 1: out bf16, raw
// ---------------------------------------------------------------------------
template<int MODE>
__global__ __launch_bounds__(256) void gemm128(
    const __bf16* __restrict__ A,  int lda, long sAb,
    const __bf16* __restrict__ Bt, int ldb, long sBb,
    void* __restrict__ Cout, int ldc, long sCb,
    int M, int N, int K,
    const float* __restrict__ bias,
    const float* __restrict__ scale,
    const float* __restrict__ addx)
{
    const int z = blockIdx.z;
    const __bf16* Ab = A  + (long)z * sAb;
    const __bf16* Bb = Bt + (long)z * sBb;

    const int nwg = gridDim.x * gridDim.y;
    const int lin = blockIdx.y * gridDim.x + blockIdx.x;
    const int qd = nwg >> 3, rr = nwg & 7, xc = lin & 7, oo = lin >> 3;
    const int wg = (xc < rr ? xc * (qd + 1) : rr * (qd + 1) + (xc - rr) * qd) + oo;
    const int m0 = (wg / gridDim.x) * 128;
    const int n0 = (wg % gridDim.x) * 128;

    const int t  = threadIdx.x;
    const int w  = t >> 6;
    const int l  = t & 63;
    const int lr = l & 15;
    const int q  = l >> 4;
    const int xr = (lr >> 1) & 3;

    __shared__ __align__(16) __bf16 sa[3][128 * 32];
    __shared__ __align__(16) __bf16 sb[3][128 * 32];

    floatx4 acc[4][4] = {};

    const int wm = (w & 1) * 64;
    const int wn = (w >> 1) * 64;

    const int srow = l >> 2;
    const int skc  = ((l & 3) ^ ((l >> 3) & 3)) * 8;

    int arow0 = m0 + w * 16 + srow;        if (arow0 > M - 1) arow0 = M - 1;
    int arow1 = m0 + (w + 4) * 16 + srow;  if (arow1 > M - 1) arow1 = M - 1;
    int brow0 = n0 + w * 16 + srow;        if (brow0 > N - 1) brow0 = N - 1;
    int brow1 = n0 + (w + 4) * 16 + srow;  if (brow1 > N - 1) brow1 = N - 1;

    const __bf16* agp0 = Ab + (long)arow0 * lda + skc;
    const __bf16* agp1 = Ab + (long)arow1 * lda + skc;
    const __bf16* bgp0 = Bb + (long)brow0 * ldb + skc;
    const __bf16* bgp1 = Bb + (long)brow1 * ldb + skc;

    auto issue = [&](int slot, int cc) {
        const int k0 = cc * 32;
        gload_lds16(agp0 + k0, &sa[slot][(size_t)w * 512]);
        gload_lds16(agp1 + k0, &sa[slot][(size_t)(w + 4) * 512]);
        gload_lds16(bgp0 + k0, &sb[slot][(size_t)w * 512]);
        gload_lds16(bgp1 + k0, &sb[slot][(size_t)(w + 4) * 512]);
    };

    auto compute = [&](int slot) {
        bf16x8 af[4], bfv[4];
#pragma unroll
        for (int i = 0; i < 4; ++i)
            af[i] = *reinterpret_cast<const bf16x8*>(
                &sa[slot][(wm + i * 16 + lr) * 32 + ((q ^ xr) * 8)]);
#pragma unroll
        for (int j = 0; j < 4; ++j)
            bfv[j] = *reinterpret_cast<const bf16x8*>(
                &sb[slot][(wn + j * 16 + lr) * 32 + ((q ^ xr) * 8)]);
#pragma unroll
        for (int i = 0; i < 4; ++i)
#pragma unroll
            for (int j = 0; j < 4; ++j)
                acc[i][j] = __builtin_amdgcn_mfma_f32_16x16x32_bf16(af[i], bfv[j], acc[i][j], 0, 0, 0);
    };

    const int NC = K >> 5;

    issue(0, 0);
    issue(1, 1);
    asm volatile("s_waitcnt vmcnt(4)" ::: "memory");
    __builtin_amdgcn_sched_barrier(0);
    __builtin_amdgcn_s_barrier();
    __builtin_amdgcn_sched_barrier(0);

#pragma unroll 3
    for (int c = 0; c < NC; ++c) {
        const int cs = c % 3;
        if (c + 2 < NC) issue((c + 2) % 3, c + 2);
        compute(cs);
        if (c + 1 < NC) {
            if (c + 2 < NC) asm volatile("s_waitcnt vmcnt(4)" ::: "memory");
            else            asm volatile("s_waitcnt vmcnt(0)" ::: "memory");
            __builtin_amdgcn_sched_barrier(0);
            __builtin_amdgcn_s_barrier();
            __builtin_amdgcn_sched_barrier(0);
        }
    }

#pragma unroll
    for (int i = 0; i < 4; ++i) {
        const int mbase = m0 + wm + i * 16 + q * 4;
#pragma unroll
        for (int j = 0; j < 4; ++j) {
            const int n = n0 + wn + j * 16 + lr;
#pragma unroll
            for (int r = 0; r < 4; ++r) {
                const int m = mbase + r;
                if (m < M && n < N) {
                    float v = acc[i][j][r];
                    ((__bf16*)Cout)[(long)z * sCb + (long)m * ldc + n] = (__bf16)v;
                }
            }
        }
    }
}

// ---------------------------------------------------------------------------
// Fused: x (f32) -> xb (bf16)  AND  xbT[b][c][m] (m padded to 192) transpose.
// ---------------------------------------------------------------------------
__global__ __launch_bounds__(256) void convert_transpose_x(
    const float* __restrict__ x, __bf16* __restrict__ xb, __bf16* __restrict__ xbT)
{
    const int c0 = (blockIdx.x % 12) * 64;
    const int b  = blockIdx.x / 12;
    __shared__ __bf16 lds[64 * 194];
    const int t = threadIdx.x;

    for (int i = 0; i < 12; ++i) {
        int idx = i * 256 + t;
        if (idx < 2880) {
            int m = idx >> 4, c4 = idx & 15;
            float4 v = *reinterpret_cast<const float4*>(
                &x[((long)(b * NN + m)) * CC + c0 + c4 * 4]);
            bf16x4 o;
            o[0] = (__bf16)v.x; o[1] = (__bf16)v.y;
            o[2] = (__bf16)v.z; o[3] = (__bf16)v.w;
            *reinterpret_cast<bf16x4*>(&xb[((long)(b * NN + m)) * CC + c0 + c4 * 4]) = o;
            lds[(c4 * 4 + 0) * 194 + m] = o[0];
            lds[(c4 * 4 + 1) * 194 + m] = o[1];
            lds[(c4 * 4 + 2) * 194 + m] = o[2];
            lds[(c4 * 4 + 3) * 194 + m] = o[3];
        }
    }
    __syncthreads();
    for (int j = 0; j < 48; ++j) {
        int idx = j * 256 + t;
        int c = idx / KPAD, m = idx % KPAD;
        __bf16 v = (m < NN) ? lds[c * 194 + m] : (__bf16)0.0f;
        xbT[((long)(b * CC + c0 + c)) * KPAD + m] = v;
    }
}

// ---------------------------------------------------------------------------
__global__ __launch_bounds__(256) void prep_weights(
    const float* __restrict__ Wq, const float* __restrict__ bq,
    const float* __restrict__ Wk, const float* __restrict__ bk,
    const float* __restrict__ Wg,
    __bf16* __restrict__ WqkT, __bf16* __restrict__ WgT,
    float* __restrict__ biasqk, float* __restrict__ scaleqk)
{
    int blk = blockIdx.x, t = threadIdx.x;
    if (blk < 384) {
        int n = blk;
        const float* W = (n < RR) ? Wq : Wk;
        int nn = (n < RR) ? n : n - RR;
        for (int k = t; k < CC; k += 256)
            WqkT[(long)n * CC + k] = (__bf16)W[(long)k * RR + nn];
        if (blk == 0) {
            for (int i = t; i < 384; i += 256) {
                biasqk[i]  = (i < RR) ? bq[i] : bk[i - RR];
                scaleqk[i] = (i < RR) ? rsqrtf((float)RR) : 1.0f;
            }
        }
    } else {
        int n = blk - 384;
        for (int k = t; k < CC; k += 256)
            WgT[(long)n * CC + k] = (__bf16)Wg[(long)k * CC + n];
    }
}

// ---------------------------------------------------------------------------
__global__ __launch_bounds__(256) void softmax_combine(
    const __bf16* __restrict__ S, const float* __restrict__ A_phys,
    const float* __restrict__ alpha, __bf16* __restrict__ Acomb)
{
    const int w = threadIdx.x >> 6, l = threadIdx.x & 63;
    const long row = (long)blockIdx.x * 4 + w;
    const int b = (int)(row / NN), n = (int)(row % NN);
    const __bf16* Srow = S + ((long)b * NN + n) * NN;

    float v[3];
#pragma unroll
    for (int i = 0; i < 3; ++i) {
        int m = l + 64 * i;
        v[i] = (m < NN) ? (float)Srow[m] : -1e30f;
    }
    float mx = fmaxf(fmaxf(v[0], v[1]), v[2]);
    for (int off = 32; off; off >>= 1) mx = fmaxf(mx, __shfl_xor(mx, off, 64));

    float e[3], sum = 0.f;
#pragma unroll
    for (int i = 0; i < 3; ++i) {
        int m = l + 64 * i;
        e[i] = (m < NN) ? expf(v[i] - mx) : 0.f;
        sum += e[i];
    }
    for (int off = 32; off; off >>= 1) sum += __shfl_xor(sum, off, 64);

    const float a   = 1.f / (1.f + expf(-alpha[0]));
    const float inv = (1.f - a) / sum;
    __bf16* Orow = Acomb + ((long)b * NN + n) * KPAD;
#pragma unroll
    for (int i = 0; i < 3; ++i) {
        int m = l + 64 * i;
        if (m < KPAD) {
            float o = (m < NN) ? (a * A_phys[n * NN + m] + e[i] * inv) : 0.f;
            Orow[m] = (__bf16)o;
        }
    }
}

// ---------------------------------------------------------------------------
__global__ __launch_bounds__(256) void ln_kernel(float* __restrict__ out,
                                                 const float* __restrict__ gamma,
                                                 const float* __restrict__ beta)
{
    float* p = out + (long)blockIdx.x * CC;
    const int t = threadIdx.x, w = t >> 6, l = t & 63;
    float h[3], s = 0.f, s2 = 0.f;
#pragma unroll
    for (int i = 0; i < 3; ++i) {
        h[i] = p[t + 256 * i];
        s += h[i]; s2 += h[i] * h[i];
    }
    for (int off = 32; off; off >>= 1) { s += __shfl_xor(s, off, 64); s2 += __shfl_xor(s2, off, 64); }
    __shared__ float ps[4], ps2[4];
    if (l == 0) { ps[w] = s; ps2[w] = s2; }
    __syncthreads();
    s  = ps[0] + ps[1] + ps[2] + ps[3];
    s2 = ps2[0] + ps2[1] + ps2[2] + ps2[3];
    const float mu  = s * (1.f / CC);
    const float var = s2 * (1.f / CC) - mu * mu;
    const float rs  = rsqrtf(var + 1e-5f);
#pragma unroll
    for (int i = 0; i < 3; ++i) {
        int c = t + 256 * i;
        p[c] = (h[i] - mu) * rs * gamma[c] + beta[c];
    }
}

// ---------------------------------------------------------------------------
extern "C" void kernel_launch(void* const* d_in, const int* in_sizes, int n_in,
                              void* d_out, int out_size, void* d_ws, size_t ws_size,
                              hipStream_t stream)
{
    const float* x      = (const float*)d_in[0];
    const float* Wq     = (const float*)d_in[1];
    const float* bq     = (const float*)d_in[2];
    const float* Wk     = (const float*)d_in[3];
    const float* bk     = (const float*)d_in[4];
    const float* Wg     = (const float*)d_in[5];
    const float* bg     = (const float*)d_in[6];
    const float* gamma  = (const float*)d_in[7];
    const float* beta   = (const float*)d_in[8];
    const float* alpha  = (const float*)d_in[9];
    const float* A_phys = (const float*)d_in[10];

    // allow 72 KB dynamic LDS for gemm256m (one-time)
    static bool attr_done = false;
    if (!attr_done) {
        auto k0 = gemm256m<0>;
        auto k3 = gemm256m<3>;
        hipFuncSetAttribute((const void*)k0, hipFuncAttributeMaxDynamicSharedMemorySize, 73728);
        hipFuncSetAttribute((const void*)k3, hipFuncAttributeMaxDynamicSharedMemorySize, 73728);
        attr_done = true;
    }

    // ---- workspace carve (bytes). Lifetime aliases: z over xb, Acomb over QK.
    char* w = (char*)d_ws;
    __bf16* xb    = (__bf16*)(w + 0);                       // 70,778,880  (also z)
    __bf16* zbuf  = xb;
    __bf16* xbT   = (__bf16*)(w + 70778880);                // 75,497,472
    __bf16* QK    = (__bf16*)(w + 146276352);               // 35,389,440  (also Acomb)
    __bf16* Acomb = QK;
    __bf16* S     = (__bf16*)(w + 181665792);               // 16,588,800
    __bf16* WqkT  = (__bf16*)(w + 198254592);               //    589,824
    __bf16* WgT   = (__bf16*)(w + 198844416);               //  1,179,648
    float*  biasqk  = (float*)(w + 200024064);              //      1,536
    float*  scaleqk = (float*)(w + 200025600);              //      1,536

    // 1) weight prep + fused x convert/transpose
    prep_weights<<<384 + CC, 256, 0, stream>>>(Wq, bq, Wk, bk, Wg, WqkT, WgT, biasqk, scaleqk);
    convert_transpose_x<<<BB * 12, 256, 0, stream>>>(x, xb, xbT);

    // 2) GEMM1: [46080,768] @ WqkT^T -> QK [46080,384] bf16 (Q scaled by 1/sqrt(R))
    gemm256m<0><<<dim3(384 / 128, MROWS / 256, 1), 256, 73728, stream>>>(
        xb, CC, WqkT, CC, QK, 384,
        MROWS, 384, CC, biasqk, scaleqk, nullptr);

    // 3) GEMM2 (batched): S[b] = Q[b] (180x192) @ K[b]^T -> [180,180] bf16
    gemm128<1><<<dim3(2, 2, BB), 256, 0, stream>>>(
        QK, 384, (long)NN * 384, QK + RR, 384, (long)NN * 384,
        S, NN, (long)NN * NN,
        NN, NN, RR, nullptr, nullptr, nullptr);

    // 4) softmax + alpha combine -> Acomb [B][180][192] bf16 (overwrites QK region)
    softmax_combine<<<MROWS / 4, 256, 0, stream>>>(S, A_phys, alpha, Acomb);

    // 5) GEMM3 (batched): z[b] = Acomb[b] (180x192) @ xbT[b]^T (192x768) -> bf16
    gemm128<1><<<dim3(CC / 128, 2, BB), 256, 0, stream>>>(
        Acomb, KPAD, (long)NN * KPAD, xbT, KPAD, (long)CC * KPAD,
        zbuf, CC, (long)NN * CC,
        NN, CC, KPAD, nullptr, nullptr, nullptr);

    // 6) GEMM4: h = x + relu(z @ Wg + bg) -> d_out f32 [46080,768]
    gemm256m<3><<<dim3(CC / 128, MROWS / 256, 1), 256, 73728, stream>>>(
        zbuf, CC, WgT, CC, d_out, CC,
        MROWS, CC, CC, bg, nullptr, x);

    // 7) in-place LayerNorm
    ln_kernel<<<MROWS, 256, 0, stream>>>((float*)d_out, gamma, beta);
}

// Round 8
// 671.153 us; speedup vs baseline: 1.0430x; 1.0430x over previous
//
#include <hip/hip_runtime.h>
#include <hip/hip_bf16.h>
#include <math.h>
#include <stdint.h>

// Problem constants
#define BB   256
#define NN   180
#define CC   768
#define RR   192
#define MROWS (BB*NN)      // 46080 flat rows
#define KPAD 192           // node-dim padded to 192 for GEMM3 K

typedef __attribute__((ext_vector_type(8))) __bf16 bf16x8;
typedef __attribute__((ext_vector_type(4))) __bf16 bf16x4;
typedef __attribute__((ext_vector_type(4))) float  floatx4;

// async global->LDS, 16 B per lane. LDS dest is wave-uniform base + lane*16.
__device__ __forceinline__ void gload_lds16(const __bf16* g, __bf16* lds)
{
    __builtin_amdgcn_global_load_lds(
        (const __attribute__((address_space(1))) void*)(uintptr_t)(const void*)g,
        (__attribute__((address_space(3))) void*)(uintptr_t)(void*)lds,
        16, 0, 0);
}

// ---------------------------------------------------------------------------
// 128x128-tile bf16 MFMA GEMM, B transposed (Bt[n][k]). R3-VERIFIED SOURCE.
// 4 waves, each computes a 64x64 patch (4x4 grid of 16x16x32 MFMA).
// 3-slot LDS ring with COUNTED vmcnt (T4); T2 source-preswizzle (bank
// conflicts = 0); T1 bijective XCD chunking (FETCH 284->118 MB).
// MODE 0: out bf16, val=(acc+bias[n])*scale[n]            (Q/K projection)
// MODE 1: out bf16, raw                                    (scores / z)
// MODE 3: out f32,  val=relu(acc+bias[n]) + addx[m*ldc+n]  (z@Wg + residual)
// ---------------------------------------------------------------------------
template<int MODE>
__global__ __launch_bounds__(256) void gemm128(
    const __bf16* __restrict__ A,  int lda, long sAb,
    const __bf16* __restrict__ Bt, int ldb, long sBb,
    void* __restrict__ Cout, int ldc, long sCb,
    int M, int N, int K,
    const float* __restrict__ bias,
    const float* __restrict__ scale,
    const float* __restrict__ addx)
{
    const int z = blockIdx.z;
    const __bf16* Ab = A  + (long)z * sAb;
    const __bf16* Bb = Bt + (long)z * sBb;

    const int nwg = gridDim.x * gridDim.y;
    const int lin = blockIdx.y * gridDim.x + blockIdx.x;
    const int qd = nwg >> 3, rr = nwg & 7, xc = lin & 7, oo = lin >> 3;
    const int wg = (xc < rr ? xc * (qd + 1) : rr * (qd + 1) + (xc - rr) * qd) + oo;
    const int m0 = (wg / gridDim.x) * 128;
    const int n0 = (wg % gridDim.x) * 128;

    const int t  = threadIdx.x;
    const int w  = t >> 6;
    const int l  = t & 63;
    const int lr = l & 15;
    const int q  = l >> 4;
    const int xr = (lr >> 1) & 3;

    __shared__ __align__(16) __bf16 sa[3][128 * 32];
    __shared__ __align__(16) __bf16 sb[3][128 * 32];

    floatx4 acc[4][4] = {};

    const int wm = (w & 1) * 64;
    const int wn = (w >> 1) * 64;

    const int srow = l >> 2;
    const int skc  = ((l & 3) ^ ((l >> 3) & 3)) * 8;

    int arow0 = m0 + w * 16 + srow;        if (arow0 > M - 1) arow0 = M - 1;
    int arow1 = m0 + (w + 4) * 16 + srow;  if (arow1 > M - 1) arow1 = M - 1;
    int brow0 = n0 + w * 16 + srow;        if (brow0 > N - 1) brow0 = N - 1;
    int brow1 = n0 + (w + 4) * 16 + srow;  if (brow1 > N - 1) brow1 = N - 1;

    const __bf16* agp0 = Ab + (long)arow0 * lda + skc;
    const __bf16* agp1 = Ab + (long)arow1 * lda + skc;
    const __bf16* bgp0 = Bb + (long)brow0 * ldb + skc;
    const __bf16* bgp1 = Bb + (long)brow1 * ldb + skc;

    auto issue = [&](int slot, int cc) {
        const int k0 = cc * 32;
        gload_lds16(agp0 + k0, &sa[slot][(size_t)w * 512]);
        gload_lds16(agp1 + k0, &sa[slot][(size_t)(w + 4) * 512]);
        gload_lds16(bgp0 + k0, &sb[slot][(size_t)w * 512]);
        gload_lds16(bgp1 + k0, &sb[slot][(size_t)(w + 4) * 512]);
    };

    auto compute = [&](int slot) {
        bf16x8 af[4], bfv[4];
#pragma unroll
        for (int i = 0; i < 4; ++i)
            af[i] = *reinterpret_cast<const bf16x8*>(
                &sa[slot][(wm + i * 16 + lr) * 32 + ((q ^ xr) * 8)]);
#pragma unroll
        for (int j = 0; j < 4; ++j)
            bfv[j] = *reinterpret_cast<const bf16x8*>(
                &sb[slot][(wn + j * 16 + lr) * 32 + ((q ^ xr) * 8)]);
#pragma unroll
        for (int i = 0; i < 4; ++i)
#pragma unroll
            for (int j = 0; j < 4; ++j)
                acc[i][j] = __builtin_amdgcn_mfma_f32_16x16x32_bf16(af[i], bfv[j], acc[i][j], 0, 0, 0);
    };

    const int NC = K >> 5;

    issue(0, 0);
    issue(1, 1);
    asm volatile("s_waitcnt vmcnt(4)" ::: "memory");
    __builtin_amdgcn_sched_barrier(0);
    __builtin_amdgcn_s_barrier();
    __builtin_amdgcn_sched_barrier(0);

#pragma unroll 3
    for (int c = 0; c < NC; ++c) {
        const int cs = c % 3;
        if (c + 2 < NC) issue((c + 2) % 3, c + 2);
        compute(cs);
        if (c + 1 < NC) {
            if (c + 2 < NC) asm volatile("s_waitcnt vmcnt(4)" ::: "memory");
            else            asm volatile("s_waitcnt vmcnt(0)" ::: "memory");
            __builtin_amdgcn_sched_barrier(0);
            __builtin_amdgcn_s_barrier();
            __builtin_amdgcn_sched_barrier(0);
        }
    }

#pragma unroll
    for (int i = 0; i < 4; ++i) {
        const int mbase = m0 + wm + i * 16 + q * 4;
#pragma unroll
        for (int j = 0; j < 4; ++j) {
            const int n = n0 + wn + j * 16 + lr;
#pragma unroll
            for (int r = 0; r < 4; ++r) {
                const int m = mbase + r;
                if (m < M && n < N) {
                    float v = acc[i][j][r];
                    if (MODE == 0) {
                        v = (v + bias[n]) * scale[n];
                        ((__bf16*)Cout)[(long)z * sCb + (long)m * ldc + n] = (__bf16)v;
                    } else if (MODE == 1) {
                        ((__bf16*)Cout)[(long)z * sCb + (long)m * ldc + n] = (__bf16)v;
                    } else { // MODE 3
                        v = v + bias[n];
                        v = v > 0.f ? v : 0.f;
                        v += addx[(long)m * ldc + n];
                        ((float*)Cout)[(long)m * ldc + n] = v;
                    }
                }
            }
        }
    }
}

// ---------------------------------------------------------------------------
// gemm64w: 64(M)x256(N) tile for the BATCHED small-M GEMMs (M=180).
// Mechanism: 128-row tiles on M=180 compute 256 rows/batch (42% waste);
// 64-row tiles compute 192 (6.7% waste). 4 waves all at wm=0, wave w owns
// cols w*64..w*64+63 (same acc[4][4] / read map / T2 swizzle as gemm128).
// Staging: A = 4 chunks (1/wave), B = 16 chunks (4/wave). 2-slot double
// buffer with plain __syncthreads() (R2-verified loop shape, no inline asm).
// LDS 40 KB -> 4 blocks/CU. MODE 1 output only (raw bf16, batched).
// ---------------------------------------------------------------------------
__global__ __launch_bounds__(256) void gemm64w(
    const __bf16* __restrict__ A,  int lda, long sAb,
    const __bf16* __restrict__ Bt, int ldb, long sBb,
    __bf16* __restrict__ Cout, int ldc, long sCb,
    int M, int N, int K)
{
    const int z = blockIdx.z;
    const __bf16* Ab = A  + (long)z * sAb;
    const __bf16* Bb = Bt + (long)z * sBb;

    const int m0 = blockIdx.y * 64;
    const int n0 = blockIdx.x * 256;

    const int t  = threadIdx.x;
    const int w  = t >> 6;
    const int l  = t & 63;
    const int lr = l & 15;
    const int q  = l >> 4;
    const int xr = (lr >> 1) & 3;

    __shared__ __align__(16) __bf16 sa[2][64 * 32];    // 2 x 4 KB
    __shared__ __align__(16) __bf16 sb[2][256 * 32];   // 2 x 16 KB

    floatx4 acc[4][4] = {};

    const int wn = w * 64;           // wave's n-offset within tile

    // staging lane map (T2 pre-swizzle, verified): lane l -> row l>>2,
    // phys slot l&3 holds logical slot (l&3)^((l>>3)&3)
    const int srow = l >> 2;
    const int skc  = ((l & 3) ^ ((l >> 3) & 3)) * 8;

    // A: 4 chunks of 16 rows; wave w stages chunk w
    int arow = m0 + w * 16 + srow;             if (arow > M - 1) arow = M - 1;
    const __bf16* agp = Ab + (long)arow * lda + skc;

    // B: 16 chunks; wave w stages chunks w, w+4, w+8, w+12
    const __bf16* bgp[4];
#pragma unroll
    for (int j = 0; j < 4; ++j) {
        int brow = n0 + (w + j * 4) * 16 + srow;  if (brow > N - 1) brow = N - 1;
        bgp[j] = Bb + (long)brow * ldb + skc;
    }

    auto issue = [&](int slot, int cc) {
        const int k0 = cc * 32;
        gload_lds16(agp + k0, &sa[slot][(size_t)w * 512]);
#pragma unroll
        for (int j = 0; j < 4; ++j)
            gload_lds16(bgp[j] + k0, &sb[slot][(size_t)(w + j * 4) * 512]);
    };

    auto compute = [&](int slot) {
        bf16x8 af[4], bfv[4];
#pragma unroll
        for (int i = 0; i < 4; ++i)
            af[i] = *reinterpret_cast<const bf16x8*>(
                &sa[slot][(i * 16 + lr) * 32 + ((q ^ xr) * 8)]);
#pragma unroll
        for (int j = 0; j < 4; ++j)
            bfv[j] = *reinterpret_cast<const bf16x8*>(
                &sb[slot][(wn + j * 16 + lr) * 32 + ((q ^ xr) * 8)]);
#pragma unroll
        for (int i = 0; i < 4; ++i)
#pragma unroll
            for (int j = 0; j < 4; ++j)
                acc[i][j] = __builtin_amdgcn_mfma_f32_16x16x32_bf16(af[i], bfv[j], acc[i][j], 0, 0, 0);
    };

    const int NC = K >> 5;   // 6 for K=192

    issue(0, 0);
    __syncthreads();
    for (int c = 0; c < NC; ++c) {
        if (c + 1 < NC) issue((c + 1) & 1, c + 1);   // in flight during compute
        compute(c & 1);
        __syncthreads();   // reads of buf done + next buf's DMA drained
    }

    // epilogue: D subtile (i,j): row = q*4+r, col = lr
#pragma unroll
    for (int i = 0; i < 4; ++i) {
        const int mbase = m0 + i * 16 + q * 4;
#pragma unroll
        for (int j = 0; j < 4; ++j) {
            const int n = n0 + wn + j * 16 + lr;
#pragma unroll
            for (int r = 0; r < 4; ++r) {
                const int m = mbase + r;
                if (m < M && n < N)
                    Cout[(long)z * sCb + (long)m * ldc + n] = (__bf16)acc[i][j][r];
            }
        }
    }
}

// ---------------------------------------------------------------------------
// Fused: x (f32) -> xb (bf16)  AND  xbT[b][c][m] (m padded to 192) transpose.
// ---------------------------------------------------------------------------
__global__ __launch_bounds__(256) void convert_transpose_x(
    const float* __restrict__ x, __bf16* __restrict__ xb, __bf16* __restrict__ xbT)
{
    const int c0 = (blockIdx.x % 12) * 64;
    const int b  = blockIdx.x / 12;
    __shared__ __bf16 lds[64 * 194];
    const int t = threadIdx.x;

    for (int i = 0; i < 12; ++i) {
        int idx = i * 256 + t;
        if (idx < 2880) {
            int m = idx >> 4, c4 = idx & 15;
            float4 v = *reinterpret_cast<const float4*>(
                &x[((long)(b * NN + m)) * CC + c0 + c4 * 4]);
            bf16x4 o;
            o[0] = (__bf16)v.x; o[1] = (__bf16)v.y;
            o[2] = (__bf16)v.z; o[3] = (__bf16)v.w;
            *reinterpret_cast<bf16x4*>(&xb[((long)(b * NN + m)) * CC + c0 + c4 * 4]) = o;
            lds[(c4 * 4 + 0) * 194 + m] = o[0];
            lds[(c4 * 4 + 1) * 194 + m] = o[1];
            lds[(c4 * 4 + 2) * 194 + m] = o[2];
            lds[(c4 * 4 + 3) * 194 + m] = o[3];
        }
    }
    __syncthreads();
    for (int j = 0; j < 48; ++j) {
        int idx = j * 256 + t;
        int c = idx / KPAD, m = idx % KPAD;
        __bf16 v = (m < NN) ? lds[c * 194 + m] : (__bf16)0.0f;
        xbT[((long)(b * CC + c0 + c)) * KPAD + m] = v;
    }
}

// ---------------------------------------------------------------------------
__global__ __launch_bounds__(256) void prep_weights(
    const float* __restrict__ Wq, const float* __restrict__ bq,
    const float* __restrict__ Wk, const float* __restrict__ bk,
    const float* __restrict__ Wg,
    __bf16* __restrict__ WqkT, __bf16* __restrict__ WgT,
    float* __restrict__ biasqk, float* __restrict__ scaleqk)
{
    int blk = blockIdx.x, t = threadIdx.x;
    if (blk < 384) {
        int n = blk;
        const float* W = (n < RR) ? Wq : Wk;
        int nn = (n < RR) ? n : n - RR;
        for (int k = t; k < CC; k += 256)
            WqkT[(long)n * CC + k] = (__bf16)W[(long)k * RR + nn];
        if (blk == 0) {
            for (int i = t; i < 384; i += 256) {
                biasqk[i]  = (i < RR) ? bq[i] : bk[i - RR];
                scaleqk[i] = (i < RR) ? rsqrtf((float)RR) : 1.0f;
            }
        }
    } else {
        int n = blk - 384;
        for (int k = t; k < CC; k += 256)
            WgT[(long)n * CC + k] = (__bf16)Wg[(long)k * CC + n];
    }
}

// ---------------------------------------------------------------------------
__global__ __launch_bounds__(256) void softmax_combine(
    const __bf16* __restrict__ S, const float* __restrict__ A_phys,
    const float* __restrict__ alpha, __bf16* __restrict__ Acomb)
{
    const int w = threadIdx.x >> 6, l = threadIdx.x & 63;
    const long row = (long)blockIdx.x * 4 + w;
    const int b = (int)(row / NN), n = (int)(row % NN);
    const __bf16* Srow = S + ((long)b * NN + n) * NN;

    float v[3];
#pragma unroll
    for (int i = 0; i < 3; ++i) {
        int m = l + 64 * i;
        v[i] = (m < NN) ? (float)Srow[m] : -1e30f;
    }
    float mx = fmaxf(fmaxf(v[0], v[1]), v[2]);
    for (int off = 32; off; off >>= 1) mx = fmaxf(mx, __shfl_xor(mx, off, 64));

    float e[3], sum = 0.f;
#pragma unroll
    for (int i = 0; i < 3; ++i) {
        int m = l + 64 * i;
        e[i] = (m < NN) ? expf(v[i] - mx) : 0.f;
        sum += e[i];
    }
    for (int off = 32; off; off >>= 1) sum += __shfl_xor(sum, off, 64);

    const float a   = 1.f / (1.f + expf(-alpha[0]));
    const float inv = (1.f - a) / sum;
    __bf16* Orow = Acomb + ((long)b * NN + n) * KPAD;
#pragma unroll
    for (int i = 0; i < 3; ++i) {
        int m = l + 64 * i;
        if (m < KPAD) {
            float o = (m < NN) ? (a * A_phys[n * NN + m] + e[i] * inv) : 0.f;
            Orow[m] = (__bf16)o;
        }
    }
}

// ---------------------------------------------------------------------------
__global__ __launch_bounds__(256) void ln_kernel(float* __restrict__ out,
                                                 const float* __restrict__ gamma,
                                                 const float* __restrict__ beta)
{
    float* p = out + (long)blockIdx.x * CC;
    const int t = threadIdx.x, w = t >> 6, l = t & 63;
    float h[3], s = 0.f, s2 = 0.f;
#pragma unroll
    for (int i = 0; i < 3; ++i) {
        h[i] = p[t + 256 * i];
        s += h[i]; s2 += h[i] * h[i];
    }
    for (int off = 32; off; off >>= 1) { s += __shfl_xor(s, off, 64); s2 += __shfl_xor(s2, off, 64); }
    __shared__ float ps[4], ps2[4];
    if (l == 0) { ps[w] = s; ps2[w] = s2; }
    __syncthreads();
    s  = ps[0] + ps[1] + ps[2] + ps[3];
    s2 = ps2[0] + ps2[1] + ps2[2] + ps2[3];
    const float mu  = s * (1.f / CC);
    const float var = s2 * (1.f / CC) - mu * mu;
    const float rs  = rsqrtf(var + 1e-5f);
#pragma unroll
    for (int i = 0; i < 3; ++i) {
        int c = t + 256 * i;
        p[c] = (h[i] - mu) * rs * gamma[c] + beta[c];
    }
}

// ---------------------------------------------------------------------------
extern "C" void kernel_launch(void* const* d_in, const int* in_sizes, int n_in,
                              void* d_out, int out_size, void* d_ws, size_t ws_size,
                              hipStream_t stream)
{
    const float* x      = (const float*)d_in[0];
    const float* Wq     = (const float*)d_in[1];
    const float* bq     = (const float*)d_in[2];
    const float* Wk     = (const float*)d_in[3];
    const float* bk     = (const float*)d_in[4];
    const float* Wg     = (const float*)d_in[5];
    const float* bg     = (const float*)d_in[6];
    const float* gamma  = (const float*)d_in[7];
    const float* beta   = (const float*)d_in[8];
    const float* alpha  = (const float*)d_in[9];
    const float* A_phys = (const float*)d_in[10];

    // ---- workspace carve (bytes). Lifetime aliases: z over xb, Acomb over QK.
    char* w = (char*)d_ws;
    __bf16* xb    = (__bf16*)(w + 0);                       // 70,778,880  (also z)
    __bf16* zbuf  = xb;
    __bf16* xbT   = (__bf16*)(w + 70778880);                // 75,497,472
    __bf16* QK    = (__bf16*)(w + 146276352);               // 35,389,440  (also Acomb)
    __bf16* Acomb = QK;
    __bf16* S     = (__bf16*)(w + 181665792);               // 16,588,800
    __bf16* WqkT  = (__bf16*)(w + 198254592);               //    589,824
    __bf16* WgT   = (__bf16*)(w + 198844416);               //  1,179,648
    float*  biasqk  = (float*)(w + 200024064);              //      1,536
    float*  scaleqk = (float*)(w + 200025600);              //      1,536

    // 1) weight prep + fused x convert/transpose
    prep_weights<<<384 + CC, 256, 0, stream>>>(Wq, bq, Wk, bk, Wg, WqkT, WgT, biasqk, scaleqk);
    convert_transpose_x<<<BB * 12, 256, 0, stream>>>(x, xb, xbT);

    // 2) GEMM1: [46080,768] @ WqkT^T -> QK [46080,384] bf16 (Q scaled by 1/sqrt(R))
    gemm128<0><<<dim3(384 / 128, MROWS / 128, 1), 256, 0, stream>>>(
        xb, CC, 0L, WqkT, CC, 0L, QK, 384, 0L,
        MROWS, 384, CC, biasqk, scaleqk, nullptr);

    // 3) GEMM2 (batched): S[b] = Q[b] (180x192) @ K[b]^T -> [180,180] bf16
    //    64x256 tile: computed 192x256 vs 256x256 before.
    gemm64w<<<dim3(1, 3, BB), 256, 0, stream>>>(
        QK, 384, (long)NN * 384, QK + RR, 384, (long)NN * 384,
        S, NN, (long)NN * NN,
        NN, NN, RR);

    // 4) softmax + alpha combine -> Acomb [B][180][192] bf16 (overwrites QK region)
    softmax_combine<<<MROWS / 4, 256, 0, stream>>>(S, A_phys, alpha, Acomb);

    // 5) GEMM3 (batched): z[b] = Acomb[b] (180x192) @ xbT[b]^T (192x768) -> bf16
    //    64x256 tile: computed rows 192 vs 256 (waste 42% -> 6.7%).
    gemm64w<<<dim3(CC / 256, 3, BB), 256, 0, stream>>>(
        Acomb, KPAD, (long)NN * KPAD, xbT, KPAD, (long)CC * KPAD,
        zbuf, CC, (long)NN * CC,
        NN, CC, KPAD);

    // 6) GEMM4: h = x + relu(z @ Wg + bg) -> d_out f32 [46080,768]
    gemm128<3><<<dim3(CC / 128, MROWS / 128, 1), 256, 0, stream>>>(
        zbuf, CC, 0L, WgT, CC, 0L, d_out, CC, 0L,
        MROWS, CC, CC, bg, nullptr, x);

    // 7) in-place LayerNorm
    ln_kernel<<<MROWS, 256, 0, stream>>>((float*)d_out, gamma, beta);
}